// Round 1
// baseline (1199.250 us; speedup 1.0000x reference)
//
#include <hip/hip_runtime.h>
#include <hip/hip_bf16.h>

// GNN layer decomposition:
//   S = hidden @ Ws.T            (n_node x 32)   -- per-sub attn projection
//   R = rela_embed @ Wr.T        (n_rel  x 32)   -- per-rel attn projection
//   Q[b] = rela[q_rel[b]] @ Wqr.T + bqr (8 x 32) -- per-batch attn projection
//   per edge: alpha = sigmoid(dot(w_alpha, relu(S[sub]+R[rel]+Q[r_idx])) + b)
//             agg[obj] += alpha * (hidden[sub] + rela[rel])   (atomicAdd f32)
//   out = agg @ Wh.T             (n_node x 64)

__global__ void proj32_kernel(const float* __restrict__ X, const float* __restrict__ W,
                              float* __restrict__ out, int nrows) {
    // out[n][k] = sum_d X[n][d] * W[k][d],  k<32, d<64
    __shared__ float wT[64 * 32];           // wT[d*32+k] = W[k*64+d]
    int tid = threadIdx.x;
    for (int i = tid; i < 32 * 64; i += 256) {
        int k = i >> 6, d = i & 63;
        wT[d * 32 + k] = W[i];
    }
    __syncthreads();
    int row = blockIdx.x * 8 + (tid >> 5);  // 8 rows per block
    int k = tid & 31;
    if (row >= nrows) return;
    const float4* X4 = (const float4*)(X + (size_t)row * 64);
    float acc = 0.f;
#pragma unroll
    for (int d4 = 0; d4 < 16; ++d4) {
        float4 x = X4[d4];                  // broadcast across the 32 lanes sharing row
        int d = d4 * 4;
        acc += x.x * wT[(d + 0) * 32 + k] + x.y * wT[(d + 1) * 32 + k]
             + x.z * wT[(d + 2) * 32 + k] + x.w * wT[(d + 3) * 32 + k];
    }
    out[(size_t)row * 32 + k] = acc;
}

__global__ void qproj_kernel(const int* __restrict__ q_rel, const float* __restrict__ rela,
                             const float* __restrict__ Wqr, const float* __restrict__ bqr,
                             float* __restrict__ Q, int batch) {
    int tid = threadIdx.x;
    int b = tid >> 5, k = tid & 31;
    if (b >= batch) return;
    int qr = q_rel[b];
    const float* x = rela + (size_t)qr * 64;
    const float* w = Wqr + (size_t)k * 64;
    float acc = bqr[k];
    for (int d = 0; d < 64; ++d) acc += w[d] * x[d];
    Q[b * 32 + k] = acc;
}

__global__ void edge_kernel(const int* __restrict__ edges, const float* __restrict__ S,
                            const float* __restrict__ R, const float* __restrict__ Q,
                            const float* __restrict__ hidden, const float* __restrict__ rela,
                            const float* __restrict__ w_alpha_w,
                            const float* __restrict__ w_alpha_b,
                            float* __restrict__ agg, int n_edge) {
    int tid = threadIdx.x;
    int lane = tid & 31;                     // 32 lanes cooperate on one edge
    int e = blockIdx.x * 8 + (tid >> 5);     // 8 edges per 256-thread block
    if (e >= n_edge) return;
    const int* er = edges + (size_t)e * 6;
    int ridx = er[0];
    int rel  = er[2];
    int sub  = er[4];
    int obj  = er[5];

    // attention logit: relu(S[sub]+R[rel]+Q[ridx]) . w_alpha
    float a = S[(size_t)sub * 32 + lane] + R[(size_t)rel * 32 + lane] + Q[ridx * 32 + lane];
    a = fmaxf(a, 0.f);
    float p = a * w_alpha_w[lane];
#pragma unroll
    for (int off = 16; off > 0; off >>= 1) p += __shfl_xor(p, off, 32);
    float alpha = 1.f / (1.f + __expf(-(p + w_alpha_b[0])));

    // message = alpha * (hidden[sub] + rela[rel]); each lane handles 2 floats
    const float2* h2 = (const float2*)hidden + (size_t)sub * 32 + lane;
    const float2* r2 = (const float2*)rela + (size_t)rel * 32 + lane;
    float2 h = *h2;
    float2 r = *r2;
    float* dst = agg + (size_t)obj * 64 + lane * 2;
    atomicAdd(dst,     alpha * (h.x + r.x));
    atomicAdd(dst + 1, alpha * (h.y + r.y));
}

__global__ void outgemm_kernel(const float* __restrict__ agg, const float* __restrict__ Wh,
                               float* __restrict__ out, int nrows) {
    // out[n][j] = sum_d agg[n][d] * Wh[j][d],  j<64, d<64
    __shared__ float wT[64 * 64];           // wT[d*64+j] = Wh[j*64+d]
    int tid = threadIdx.x;
    for (int i = tid; i < 64 * 64; i += 256) {
        int j = i >> 6, d = i & 63;
        wT[d * 64 + j] = Wh[i];
    }
    __syncthreads();
    int row = blockIdx.x * 4 + (tid >> 6);  // 4 rows per block
    int j = tid & 63;
    if (row >= nrows) return;
    const float4* A4 = (const float4*)(agg + (size_t)row * 64);
    float acc = 0.f;
#pragma unroll
    for (int d4 = 0; d4 < 16; ++d4) {
        float4 x = A4[d4];
        int d = d4 * 4;
        acc += x.x * wT[(d + 0) * 64 + j] + x.y * wT[(d + 1) * 64 + j]
             + x.z * wT[(d + 2) * 64 + j] + x.w * wT[(d + 3) * 64 + j];
    }
    out[(size_t)row * 64 + j] = acc;
}

extern "C" void kernel_launch(void* const* d_in, const int* in_sizes, int n_in,
                              void* d_out, int out_size, void* d_ws, size_t ws_size,
                              hipStream_t stream) {
    // inputs (setup_inputs order):
    // 0 q_sub (unused), 1 q_rel, 2 hidden, 3 edges, 4 nodes (unused),
    // 5 old_nodes_new_idx (unused), 6 batchsize, 7 rela_embed,
    // 8 Ws, 9 Wr, 10 Wqr, 11 bqr, 12 w_alpha_w, 13 w_alpha_b, 14 Wh
    const int*   q_rel     = (const int*)d_in[1];
    const float* hidden    = (const float*)d_in[2];
    const int*   edges     = (const int*)d_in[3];
    const float* rela      = (const float*)d_in[7];
    const float* Ws        = (const float*)d_in[8];
    const float* Wr        = (const float*)d_in[9];
    const float* Wqr       = (const float*)d_in[10];
    const float* bqr       = (const float*)d_in[11];
    const float* w_alpha_w = (const float*)d_in[12];
    const float* w_alpha_b = (const float*)d_in[13];
    const float* Wh        = (const float*)d_in[14];

    int n_node = in_sizes[2] / 64;
    int n_edge = in_sizes[3] / 6;
    int n_rel  = in_sizes[7] / 64;
    int batch  = in_sizes[1];

    // workspace layout (floats)
    float* S   = (float*)d_ws;                    // n_node*32
    float* agg = S + (size_t)n_node * 32;         // n_node*64
    float* R   = agg + (size_t)n_node * 64;       // n_rel*32
    float* Q   = R + (size_t)n_rel * 32;          // batch*32

    hipMemsetAsync(agg, 0, (size_t)n_node * 64 * sizeof(float), stream);

    proj32_kernel<<<(n_node + 7) / 8, 256, 0, stream>>>(hidden, Ws, S, n_node);
    proj32_kernel<<<(n_rel + 7) / 8, 256, 0, stream>>>(rela, Wr, R, n_rel);
    qproj_kernel<<<1, 256, 0, stream>>>(q_rel, rela, Wqr, bqr, Q, batch);

    edge_kernel<<<(n_edge + 7) / 8, 256, 0, stream>>>(edges, S, R, Q, hidden, rela,
                                                      w_alpha_w, w_alpha_b, agg, n_edge);

    outgemm_kernel<<<(n_node + 3) / 4, 256, 0, stream>>>(agg, Wh, (float*)d_out, n_node);
}